// Round 9
// baseline (100.497 us; speedup 1.0000x reference)
//
#include <hip/hip_runtime.h>
#include <stdint.h>

typedef _Float16 half8 __attribute__((ext_vector_type(8)));
typedef float f32x16 __attribute__((ext_vector_type(16)));
typedef float f32x4  __attribute__((ext_vector_type(4)));

// ---------------- layout ----------------
// th2 (ws): pre-image of the LDS B tile, 18 blobs (p = i*6 + j*2 + h2) of
//   37888 B: rows f=0..63, row stride 296 halves (288 data + 8 pad zeros);
//   data kk = h2*288 + cb -> theta[i][f][j*576 + kk], kk = c*18 + m.
//   Linear blob == linear LDS image => global_load_lds stages it with zero
//   staging registers.
// A (LDS, rebuilt EVERY phase): 32 px rows x 296 halves; row r holds the
//   288-half feature slice (c_local*18+m, c = h2*16+c_local) of input pixel
//   w = ph*32 + r + j  -- the j-shift is baked into the build, no halo rows.
// Strides 592 B: measured 0-conflict class for the b128 fragment reads (R8).
#define NTH2 340992                       // halves: 18 * 18944
#define PREP_BLOCKS (NTH2 / 256)          // 1332 exactly

__global__ __launch_bounds__(256) void kan_prep(
    const float* __restrict__ cp, const float* __restrict__ wspl,
    const float* __restrict__ wsil, _Float16* __restrict__ th2)
{
    int e  = blockIdx.x * 256 + threadIdx.x;   // < NTH2 exactly
    int p  = e / 18944;
    int r  = e - p * 18944;
    int f  = r / 296;
    int cb = r - f * 296;
    int i  = p / 6;
    int jh = p - i * 6;
    int j  = jh >> 1;
    int h2 = jh & 1;
    float v = 0.0f;
    if (cb < 288) {
        int kk = h2 * 288 + cb;
        int c  = kk / 18;
        int m  = kk - c * 18;
        int base = ((f * 32 + c) * 3 + i) * 3 + j;       // (F,C,3,3) flat
        v = (m < 17) ? wspl[base] * cp[base * 17 + m] : wsil[base];
    }
    th2[e] = (_Float16)v;
}

// Fused GEMM, atomic-free. Block = 128 thr = 2 waves (wave = f-half),
// tile 32 px x 64 f. Grid 512 = 2 blocks per output row (ph = px half),
// bx = ph*256 + (b*64+ho) so same-row siblings share an XCD's L2.
// LDS 55.5 KB -> 2 independent blocks/CU: one block's stage-wait hides
// under the other's compute (the R8 structure had 1 block/CU and every
// latency was serially exposed: 18 x 5600 cy phases, MfmaUtil 9%).
// 18 phases: p -> (i = p/6, j, h2), K-chunk 288, 18 MFMA/wave/phase.
// Single-buffered A+B per phase; plain __syncthreads (its vmcnt drain is
// exactly the single-buffer visibility requirement).
__global__ __launch_bounds__(128) void kan_main(
    const float* __restrict__ x, const _Float16* __restrict__ th2,
    const float* __restrict__ bias, float* __restrict__ out)
{
    __shared__ __align__(16) _Float16 lA[32 * 296];      // 18944 B
    __shared__ __align__(16) _Float16 lB[64 * 296];      // 37888 B

    const int bx  = blockIdx.x;                    // ph*256 + row
    const int ph  = bx >> 8;                       // px half 0/1
    const int row = bx & 255;
    const int b   = row >> 6;
    const int ho  = row & 63;

    const int tid  = threadIdx.x;                  // 0..127
    const int wf   = tid >> 6;                     // wave = f half
    const int lane = tid & 63;
    const int r31  = lane & 31;
    const int kh   = lane >> 5;

    const int ar = tid >> 2;                       // A row 0..31
    const int cq = tid & 3;                        // c-quad within h2 half

    const char* thB = (const char*)th2;
    char* lBc = (char*)lB;
    char* lAc = (char*)lA;

    f32x16 acc;
    {
        float bv = bias[wf * 32 + r31];
#pragma unroll
        for (int r = 0; r < 16; ++r) acc[r] = bv;
    }

    const _Float16* pa = lA + r31 * 296 + kh * 8;
    const _Float16* pb = lB + (wf * 32 + r31) * 296 + kh * 8;

    for (int p = 0; p < 18; ++p) {
        const int i  = p / 6;
        const int jh = p - i * 6;
        const int j  = jh >> 1;
        const int h2 = jh & 1;

        // ---- stage B blob p: 2368 units16; unit u = t*128 + tid.
        //      dst (uniform per wave) = t*2048 + wf*1024; lane*16 implicit.
        {
            const char* gs = thB + (size_t)p * 37888 + wf * 1024 + lane * 16;
            char* ld = lBc + wf * 1024;
#pragma unroll
            for (int t = 0; t < 18; ++t)
                __builtin_amdgcn_global_load_lds(
                    (const __attribute__((address_space(1))) void*)(gs + t * 2048),
                    (__attribute__((address_space(3))) void*)(ld + t * 2048),
                    16, 0, 0);
            if (wf == 0)                           // tail 1024 B (units 2304+)
                __builtin_amdgcn_global_load_lds(
                    (const __attribute__((address_space(1))) void*)(gs + 36864),
                    (__attribute__((address_space(3))) void*)(lBc + 36864),
                    16, 0, 0);
        }

        // ---- build A chunk: thread -> (row ar, c_local = cq*4..+3)
        {
            const f32x4 xv = *(const f32x4*)(
                x + ((size_t)((b * 66 + ho + i) * 66 + ph * 32 + ar + j)) * 32
                  + h2 * 16 + cq * 4);
#pragma unroll
            for (int pr = 0; pr < 2; ++pr) {       // 2 cell-pairs -> 72 B each
                union { _Float16 h[36]; uint64_t q[9]; } pk;
#pragma unroll
                for (int d = 0; d < 2; ++d) {
                    float pv = xv[pr * 2 + d];
                    float u  = fmaf(fminf(1.0f, fmaxf(-1.0f, pv)), 8.0f, 8.0f);
#pragma unroll
                    for (int m = 0; m < 17; ++m)
                        pk.h[d * 18 + m] =
                            (_Float16)fmaxf(0.0f, 1.0f - fabsf(u - (float)m));
                    pk.h[d * 18 + 17] = (_Float16)(
                        pv * __builtin_amdgcn_rcpf(1.0f + __expf(-pv)));
                }
                uint64_t* dst = (uint64_t*)(lAc + ar * 592 + cq * 144 + pr * 72);
#pragma unroll
                for (int r = 0; r < 9; ++r) dst[r] = pk.q[r];
            }
        }

        __syncthreads();                           // drains vmcnt+lgkm: A,B ready

        // ---- 18 MFMA k-steps over this (i, j, h2) chunk
#pragma unroll
        for (int s = 0; s < 18; ++s) {
            half8 a  = *(const half8*)(pa + s * 16);
            half8 bf = *(const half8*)(pb + s * 16);
            acc = __builtin_amdgcn_mfma_f32_32x32x16_f16(a, bf, acc, 0, 0, 0);
        }

        __syncthreads();                           // reads retired before restage
    }

    // C/D layout (verified): col = lane&31, row = (reg&3)+8*(reg>>2)+4*(lane>>5)
    float* obase = out
        + ((size_t)((b * 64 + ho) * 64 + ph * 32)) * 64 + wf * 32;
#pragma unroll
    for (int r = 0; r < 16; ++r) {
        int rowD = (r & 3) + 8 * (r >> 2) + 4 * kh;  // px within the 32-block
        obase[(size_t)rowD * 64 + r31] = acc[r];     // plain store
    }
}

extern "C" void kernel_launch(void* const* d_in, const int* in_sizes, int n_in,
                              void* d_out, int out_size, void* d_ws, size_t ws_size,
                              hipStream_t stream) {
    const float* x    = (const float*)d_in[0];
    const float* cp   = (const float*)d_in[1];
    const float* wspl = (const float*)d_in[2];
    const float* wsil = (const float*)d_in[3];
    const float* bias = (const float*)d_in[4];
    float* out = (float*)d_out;

    _Float16* th2 = (_Float16*)d_ws;

    kan_prep<<<PREP_BLOCKS, 256, 0, stream>>>(cp, wspl, wsil, th2);
    kan_main<<<512, 128, 0, stream>>>(x, th2, bias, out);
}